// Round 14
// baseline (333.324 us; speedup 1.0000x reference)
//
#include <hip/hip_runtime.h>
#include <hip/hip_bf16.h>

typedef __hip_bfloat16 bf16;
typedef __bf16 bf16x8 __attribute__((ext_vector_type(8)));
typedef float f32x4 __attribute__((ext_vector_type(4)));
#define NEG_BIG (-3.0e38f)
#define SC2 0.18033688011112042f   /* 0.125 * log2(e): softmax in base-2 domain */

// All inputs and the output are FLOAT32 (per reference). Intermediates
// Q,K,V,O are bf16; GEMMs run bf16 MFMA with f32 accumulate
// (measured absmax 0.0156 << 0.069 threshold).
//
// Composition of per-kernel measured bests (session journal R4-R13):
//  - qkv: R4-exact fresh-loads, single LDS buffer, 2 barriers (130.9 us,
//    393 TF = this 128^2 2-barrier structure's shape floor; all explicit
//    pipelining probes measured worse — TLP at 6 blocks/CU already hides
//    latency, prefetch regs cost occupancy on the unified VGPR/AGPR file).
//  - attn: R5 sequential paired-tile schedule (~125 us).
//  - proj (R14 change): 64x128 tile -> grid 1024 = 4 blocks/CU (was 2).
//    proj is occupancy-bound, not density-bound: doubled TLP should beat
//    the halved per-block compute density. 2-phase reg-prefetch kept.

__device__ inline void load8_f32(const float* p, float* o) {
  float4 a = *reinterpret_cast<const float4*>(p);
  float4 b = *reinterpret_cast<const float4*>(p + 4);
  o[0]=a.x; o[1]=a.y; o[2]=a.z; o[3]=a.w;
  o[4]=b.x; o[5]=b.y; o[6]=b.z; o[7]=b.w;
}
__device__ inline unsigned short f2bf_bits(float x) {
  return __builtin_bit_cast(unsigned short, __float2bfloat16(x));
}
__device__ inline unsigned pack2bf(float lo, float hi) {
  return (unsigned)f2bf_bits(lo) | ((unsigned)f2bf_bits(hi) << 16);
}
__device__ inline bf16x8 lds8(const unsigned short* p) {
  return __builtin_bit_cast(bf16x8, *reinterpret_cast<const uint4*>(p));
}
__device__ inline f32x4 mfma16(bf16x8 a, bf16x8 b, f32x4 c) {
  return __builtin_amdgcn_mfma_f32_16x16x32_bf16(a, b, c, 0, 0, 0);
}

// ---------- Kernel 1: QKV GEMM (MFMA)  X[8192,1024]f32 @ W[1024,3072]f32 + b ----------
// R4-exact: fresh loads at loop top; TLP hides latency.
__global__ __launch_bounds__(256)
void qkv_f(const float* __restrict__ X, const float* __restrict__ W,
           const float* __restrict__ bias,
           bf16* __restrict__ q, bf16* __restrict__ k, bf16* __restrict__ v)
{
  __shared__ __align__(16) unsigned short As[128][40];
  __shared__ __align__(16) unsigned short Bt[128][40];
  const int t  = threadIdx.x;
  const int wv = t >> 6, ln = t & 63;
  const int l15 = ln & 15, lg = ln >> 4;
  const int wr = wv >> 1, wc = wv & 1;

  int id = blockIdx.x;                      // 1536 = 8 * 192, XCD swizzle
  id = (id & 7) * 192 + (id >> 3);
  const int bn = id % 24, bm = id / 24;
  const int gm0 = bm * 128, gn0 = bn * 128;

  const int arow = t >> 1, akc = (t & 1) * 16;   // A: 2 thr/row, 16 f32 each
  const int bk2  = t >> 4, bn0 = (t & 15) * 8;   // B: k-pair, 8 n each
  const int kk   = 2 * bk2;

  const f32x4 zero4 = {0.f, 0.f, 0.f, 0.f};
  f32x4 acc[4][4];
#pragma unroll
  for (int m = 0; m < 4; m++)
#pragma unroll
    for (int n = 0; n < 4; n++) acc[m][n] = zero4;

  for (int kt = 0; kt < 1024; kt += 32) {
    { // A tile: f32 -> bf16
      float tmp[16];
      load8_f32(X + (size_t)(gm0 + arow) * 1024 + kt + akc, tmp);
      load8_f32(X + (size_t)(gm0 + arow) * 1024 + kt + akc + 8, tmp + 8);
      unsigned short u[16];
#pragma unroll
      for (int i = 0; i < 16; i++) u[i] = f2bf_bits(tmp[i]);
      *reinterpret_cast<uint4*>(&As[arow][akc])     = *reinterpret_cast<const uint4*>(u);
      *reinterpret_cast<uint4*>(&As[arow][akc + 8]) = *reinterpret_cast<const uint4*>(u + 8);
    }
    { // B tile: transpose W[k][n] -> Bt[n][k], packed k-pairs, chunk swizzle
      const float* wp = W + (size_t)(kt + kk) * 3072 + gn0 + bn0;
      float t0[8], t1[8];
      load8_f32(wp, t0);
      load8_f32(wp + 3072, t1);
#pragma unroll
      for (int j = 0; j < 8; j++) {
        const int n = bn0 + j;
        const int col = ((((kk >> 3) ^ ((n >> 4) & 3)) << 3) | (kk & 7));
        *reinterpret_cast<unsigned*>(&Bt[n][col]) = pack2bf(t0[j], t1[j]);
      }
    }
    __syncthreads();
    bf16x8 af[4], bfr[4];
#pragma unroll
    for (int m = 0; m < 4; m++) af[m] = lds8(&As[wr*64 + m*16 + l15][lg*8]);
#pragma unroll
    for (int n = 0; n < 4; n++) {
      const int nn = wc*64 + n*16 + l15;
      bfr[n] = lds8(&Bt[nn][(lg ^ ((nn >> 4) & 3)) << 3]);
    }
#pragma unroll
    for (int n = 0; n < 4; n++)
#pragma unroll
      for (int m = 0; m < 4; m++) acc[m][n] = mfma16(af[m], bfr[n], acc[m][n]);
    __syncthreads();
  }

#pragma unroll
  for (int nf = 0; nf < 4; nf++) {
    const int base_gc = gn0 + wc*64 + nf*16;
    const int which = base_gc >> 10;
    const int h = (base_gc & 1023) >> 6;
    const int d0 = (base_gc & 63) + l15;
    const float bvs = bias[base_gc + l15];
    bf16* dst = (which == 0) ? q : ((which == 1) ? k : v);
#pragma unroll
    for (int m = 0; m < 4; m++)
#pragma unroll
      for (int ri = 0; ri < 4; ri++) {
        const int gr = gm0 + wr*64 + m*16 + lg*4 + ri;
        const int bb = gr >> 11, s = gr & 2047;
        dst[((size_t)(bb*16 + h) * 2048 + s) * 64 + d0] =
            __float2bfloat16(acc[m][nf][ri] + bvs);
      }
  }
}

// ---------- Kernel 2: causal flash attention, paired q-tiles, swapped-QK^T ----------
// R5-exact sequential schedule. Block ia handles q-tiles {ia, 31-ia}:
// constant 33 tile-computations/block. S^T = mfma(A=K, B=Q): lane owns ONE
// q-row (l15) with 16 k-values in regs. PV: O^T = mfma(A=V^T, B=P^T).
__global__ __launch_bounds__(256, 4)
void attn_f(bf16* qo, const bf16* __restrict__ kg, const bf16* __restrict__ vg)
{
  __shared__ __align__(16) unsigned short Ks[64][72];
  __shared__ __align__(16) unsigned short Vt[64][72];
  __shared__ __align__(16) unsigned short Ps[4][16][72];

  const int t  = threadIdx.x;
  const int wv = t >> 6, ln = t & 63;
  const int l15 = ln & 15, lg = ln >> 4;
  const int ia = blockIdx.x, h = blockIdx.y, b = blockIdx.z;
  const int qtA = ia, qtB = 31 - ia;             // qtB > qtA always
  const size_t basebh = (size_t)(b * 16 + h) * 2048 * 64;
  const int qA0 = qtA * 64 + wv * 16;
  const int qB0 = qtB * 64 + wv * 16;

  auto loadq = [&](int q0, bf16x8* aq) {
    const bf16* qp = qo + basebh + (size_t)(q0 + l15) * 64 + lg * 8;
    uint4 u0 = *reinterpret_cast<const uint4*>(qp);
    uint4 u1 = *reinterpret_cast<const uint4*>(qp + 32);
    unsigned w[8] = {u0.x, u0.y, u0.z, u0.w, u1.x, u1.y, u1.z, u1.w};
    unsigned o[8];
#pragma unroll
    for (int i = 0; i < 8; i++) {
      float flo = __uint_as_float(w[i] << 16) * SC2;
      float fhi = __uint_as_float(w[i] & 0xffff0000u) * SC2;
      o[i] = pack2bf(flo, fhi);
    }
    aq[0] = __builtin_bit_cast(bf16x8, *reinterpret_cast<const uint4*>(o));
    aq[1] = __builtin_bit_cast(bf16x8, *reinterpret_cast<const uint4*>(o + 4));
  };
  bf16x8 aqA[2], aqB[2];
  loadq(qA0, aqA);
  loadq(qB0, aqB);

  const f32x4 zero4 = {0.f, 0.f, 0.f, 0.f};
  f32x4 accOA[4], accOB[4];                      // accO[f][r] = O[q=l15][d=f*16+lg*4+r]
  float mA = NEG_BIG, lA = 0.f, mB = NEG_BIG, lB = 0.f;
#pragma unroll
  for (int f = 0; f < 4; f++) { accOA[f] = zero4; accOB[f] = zero4; }

  const int kr = t >> 2, kc = (t & 3) * 16;      // K stage: 4 thr/row, 32B each
  const int vr = ln, vc = wv * 16;               // V stage: lane=kv row, wave=d chunk
  const bf16* kbase = kg + basebh;
  const bf16* vbase = vg + basebh;

  auto tile_compute = [&](int ct, int qt_this, const bf16x8* aq, f32x4* accO,
                          float& m_run, float& l_run) {
    f32x4 accS[4];
    __builtin_amdgcn_s_setprio(1);
#pragma unroll
    for (int f = 0; f < 4; f++) {
      bf16x8 b0 = lds8(&Ks[f*16 + l15][lg*8]);
      bf16x8 b1 = lds8(&Ks[f*16 + l15][32 + lg*8]);
      accS[f] = mfma16(b0, aq[0], zero4);        // A=K, B=Q -> S^T
      accS[f] = mfma16(b1, aq[1], accS[f]);
    }
    __builtin_amdgcn_s_setprio(0);

    float* s = reinterpret_cast<float*>(accS);   // s[f*4+r] = S[q=l15][k=f*16+lg*4+r]
    if (ct == qt_this) {                         // diagonal tile: causal mask
#pragma unroll
      for (int f = 0; f < 4; f++)
#pragma unroll
        for (int r = 0; r < 4; r++)
          if (f*16 + lg*4 + r > wv*16 + l15) s[f*4 + r] = NEG_BIG;
    }
    float t8[8];
#pragma unroll
    for (int i = 0; i < 8; i++) t8[i] = fmaxf(s[i], s[8 + i]);
    float t4a = fmaxf(t8[0], t8[4]), t4b = fmaxf(t8[1], t8[5]);
    float t4c = fmaxf(t8[2], t8[6]), t4d = fmaxf(t8[3], t8[7]);
    float mc = fmaxf(fmaxf(t4a, t4b), fmaxf(t4c, t4d));
    mc = fmaxf(mc, __shfl_xor(mc, 16));
    mc = fmaxf(mc, __shfl_xor(mc, 32));

    const float mn = fmaxf(m_run, mc);
    if (__any(mc > m_run)) {                     // defer-max: skip rescale if no growth
      const float al = exp2f(m_run - mn);
      float* ao = reinterpret_cast<float*>(accO);
#pragma unroll
      for (int i = 0; i < 16; i++) ao[i] *= al;
      l_run *= al;
    }
    m_run = mn;

    float ps = 0.f;
#pragma unroll
    for (int i = 0; i < 16; i++) { s[i] = exp2f(s[i] - mn); ps += s[i]; }
    ps += __shfl_xor(ps, 16);
    ps += __shfl_xor(ps, 32);
    l_run += ps;

#pragma unroll
    for (int f = 0; f < 4; f++)
#pragma unroll
      for (int c = 0; c < 2; c++)
        *reinterpret_cast<unsigned*>(&Ps[wv][l15][f*16 + lg*4 + 2*c]) =
            pack2bf(s[f*4 + 2*c], s[f*4 + 2*c + 1]);
    asm volatile("s_waitcnt lgkmcnt(0)" ::: "memory");
    __builtin_amdgcn_sched_barrier(0);

    bf16x8 ap0 = lds8(&Ps[wv][l15][lg*8]);       // B[k][col=l15] = P[l15][k]
    bf16x8 ap1 = lds8(&Ps[wv][l15][32 + lg*8]);
    __builtin_amdgcn_s_setprio(1);
#pragma unroll
    for (int f = 0; f < 4; f++) {
      bf16x8 bv0 = lds8(&Vt[f*16 + l15][lg*8]);
      bf16x8 bv1 = lds8(&Vt[f*16 + l15][32 + lg*8]);
      accO[f] = mfma16(bv0, ap0, accO[f]);
      accO[f] = mfma16(bv1, ap1, accO[f]);
    }
    __builtin_amdgcn_s_setprio(0);
  };

  uint4 k0 = *reinterpret_cast<const uint4*>(kbase + (size_t)kr * 64 + kc);
  uint4 k1 = *reinterpret_cast<const uint4*>(kbase + (size_t)kr * 64 + kc + 8);
  uint4 v0 = *reinterpret_cast<const uint4*>(vbase + (size_t)vr * 64 + vc);
  uint4 v1 = *reinterpret_cast<const uint4*>(vbase + (size_t)vr * 64 + vc + 8);

  for (int ct = 0; ct <= qtB; ct++) {
    *reinterpret_cast<uint4*>(&Ks[kr][kc])     = k0;
    *reinterpret_cast<uint4*>(&Ks[kr][kc + 8]) = k1;
    {
      unsigned w[8] = {v0.x, v0.y, v0.z, v0.w, v1.x, v1.y, v1.z, v1.w};
#pragma unroll
      for (int j = 0; j < 8; j++) {
        Vt[vc + 2*j][vr]     = (unsigned short)(w[j] & 0xffffu);
        Vt[vc + 2*j + 1][vr] = (unsigned short)(w[j] >> 16);
      }
    }
    __syncthreads();
    if (ct < qtB) {                              // issue next-tile loads early (T14)
      const size_t off = (size_t)(ct + 1) * 64 * 64;
      k0 = *reinterpret_cast<const uint4*>(kbase + off + (size_t)kr * 64 + kc);
      k1 = *reinterpret_cast<const uint4*>(kbase + off + (size_t)kr * 64 + kc + 8);
      v0 = *reinterpret_cast<const uint4*>(vbase + off + (size_t)vr * 64 + vc);
      v1 = *reinterpret_cast<const uint4*>(vbase + off + (size_t)vr * 64 + vc + 8);
    }
    tile_compute(ct, qtB, aqB, accOB, mB, lB);
    if (ct <= qtA) tile_compute(ct, qtA, aqA, accOA, mA, lA);
    __syncthreads();
  }

  const float invA = 1.f / lA, invB = 1.f / lB;
#pragma unroll
  for (int f = 0; f < 4; f++) {
    ushort4 sa, sb;
#pragma unroll
    for (int r = 0; r < 4; r++) {
      reinterpret_cast<unsigned short*>(&sa)[r] = f2bf_bits(accOA[f][r] * invA);
      reinterpret_cast<unsigned short*>(&sb)[r] = f2bf_bits(accOB[f][r] * invB);
    }
    *reinterpret_cast<ushort4*>(qo + basebh + (size_t)(qA0 + l15) * 64 + f*16 + lg*4) = sa;
    *reinterpret_cast<ushort4*>(qo + basebh + (size_t)(qB0 + l15) * 64 + f*16 + lg*4) = sb;
  }
}

// ---------- Kernel 3: projection (MFMA, 2-phase pipelined, 64x128 tile) ----------
// Grid 1024 = 4 blocks/CU (was 512 = 2/CU): proj is occupancy-bound.
__global__ __launch_bounds__(256)
void proj_f(const bf16* __restrict__ A, const float* __restrict__ W,
            const float* __restrict__ bias, float* __restrict__ out)
{
  __shared__ __align__(16) unsigned short As[64][40];
  __shared__ __align__(16) unsigned short Bt[128][40];
  const int t  = threadIdx.x;
  const int wv = t >> 6, ln = t & 63;
  const int l15 = ln & 15, lg = ln >> 4;
  const int wr = wv >> 1, wc = wv & 1;

  int id = blockIdx.x;                      // 1024 = 8 * 128, XCD swizzle
  id = (id & 7) * 128 + (id >> 3);
  const int bn = id & 7, bm = id >> 3;      // bn 0..7, bm 0..127
  const int gm0 = bm * 64, gn0 = bn * 128;

  const int arow = t >> 2, akc = (t & 3) * 8;    // A: 4 thr/row, 8 bf16 each
  const int bk2  = t >> 4, bn0 = (t & 15) * 8;
  const int kk   = 2 * bk2;

  const int gr_l = gm0 + arow;
  const int bb_l = gr_l >> 11, s_l = gr_l & 2047;
  const bf16* abase = A + ((size_t)bb_l * 16 * 2048 + (size_t)s_l) * 64;  // + h*131072 + d
  const float* wrow = W + (size_t)kk * 1024 + gn0 + bn0;

  const f32x4 zero4 = {0.f, 0.f, 0.f, 0.f};
  f32x4 acc[2][4];
#pragma unroll
  for (int m = 0; m < 2; m++)
#pragma unroll
    for (int n = 0; n < 4; n++) acc[m][n] = zero4;

  auto aptr = [&](int c) {
    const int hh = c >> 6, dd = c & 63;
    return abase + (size_t)hh * 131072 + dd;
  };

  uint4 au;
  float br0[8], br1[8];
  {
    au = *reinterpret_cast<const uint4*>(aptr(akc));
    load8_f32(wrow, br0);
    load8_f32(wrow + 1024, br1);
  }

  for (int kt = 0; kt < 1024; kt += 32) {
    *reinterpret_cast<uint4*>(&As[arow][akc]) = au;
#pragma unroll
    for (int j = 0; j < 8; j++) {
      const int n = bn0 + j;
      const int col = ((((kk >> 3) ^ ((n >> 4) & 3)) << 3) | (kk & 7));
      *reinterpret_cast<unsigned*>(&Bt[n][col]) = pack2bf(br0[j], br1[j]);
    }
    __syncthreads();
    if (kt + 32 < 1024) {
      au = *reinterpret_cast<const uint4*>(aptr(kt + 32 + akc));
      const float* wp = wrow + (size_t)(kt + 32) * 1024;
      load8_f32(wp, br0);
      load8_f32(wp + 1024, br1);
    }
    bf16x8 af[2], bfr[4];
#pragma unroll
    for (int m = 0; m < 2; m++) af[m] = lds8(&As[wr*32 + m*16 + l15][lg*8]);
#pragma unroll
    for (int n = 0; n < 4; n++) {
      const int nn = wc*64 + n*16 + l15;
      bfr[n] = lds8(&Bt[nn][(lg ^ ((nn >> 4) & 3)) << 3]);
    }
#pragma unroll
    for (int n = 0; n < 4; n++)
#pragma unroll
      for (int m = 0; m < 2; m++) acc[m][n] = mfma16(af[m], bfr[n], acc[m][n]);
    __syncthreads();
  }

#pragma unroll
  for (int nf = 0; nf < 4; nf++) {
    const int gc = gn0 + wc*64 + nf*16 + l15;
    const float bvs = bias[gc];
#pragma unroll
    for (int m = 0; m < 2; m++)
#pragma unroll
      for (int ri = 0; ri < 4; ri++) {
        const int gr = gm0 + wr*32 + m*16 + lg*4 + ri;
        out[(size_t)gr * 1024 + gc] = acc[m][nf][ri] + bvs;
      }
  }
}

extern "C" void kernel_launch(void* const* d_in, const int* in_sizes, int n_in,
                              void* d_out, int out_size, void* d_ws, size_t ws_size,
                              hipStream_t stream)
{
  const float *x = nullptr, *W_attn = nullptr, *b_attn = nullptr,
              *W_proj = nullptr, *b_proj = nullptr;
  for (int i = 0; i < n_in; i++) {
    switch (in_sizes[i]) {
      case 8388608: x      = (const float*)d_in[i]; break;  // [4,2048,1024]
      case 3145728: W_attn = (const float*)d_in[i]; break;  // [1024,3072]
      case 3072:    b_attn = (const float*)d_in[i]; break;
      case 1048576: W_proj = (const float*)d_in[i]; break;  // [1024,1024]
      case 1024:    b_proj = (const float*)d_in[i]; break;
      default: break;
    }
  }
  if (!x || !W_attn || !b_attn || !W_proj || !b_proj) {
    x = (const float*)d_in[0]; W_attn = (const float*)d_in[1];
    b_attn = (const float*)d_in[2]; W_proj = (const float*)d_in[3];
    b_proj = (const float*)d_in[4];
  }
  float* out = (float*)d_out;        // 8388608 f32 = 32 MiB

  // Memory plan (inputs never written; ws requirement 16 MiB):
  //   Q -> ws[0:16M)  bf16 BHSD      (later overwritten block-privately by O)
  //   K -> d_out bytes [0:16M)  bf16 BHSD   } dead before proj's f32 writes
  //   V -> d_out bytes [16M:32M) bf16 BHSD  }
  const size_t NE = 8388608;         // bf16 elements per 16 MiB tensor
  bf16* qb = (bf16*)d_ws;
  bf16* kb = (bf16*)d_out;
  bf16* vb = kb + NE;

  qkv_f <<<dim3(1536), 256, 0, stream>>>(x, W_attn, b_attn, qb, kb, vb);
  attn_f<<<dim3(16, 16, 4), 256, 0, stream>>>(qb, kb, vb);
  proj_f<<<dim3(1024), 256, 0, stream>>>(qb, W_proj, b_proj, out);
}

// Round 15
// 326.075 us; speedup vs baseline: 1.0222x; 1.0222x over previous
//
#include <hip/hip_runtime.h>
#include <hip/hip_bf16.h>

typedef __hip_bfloat16 bf16;
typedef __bf16 bf16x8 __attribute__((ext_vector_type(8)));
typedef float f32x4 __attribute__((ext_vector_type(4)));
#define NEG_BIG (-3.0e38f)
#define SC2 0.18033688011112042f   /* 0.125 * log2(e): softmax in base-2 domain */

// All inputs and the output are FLOAT32 (per reference). Intermediates
// Q,K,V,O are bf16; GEMMs run bf16 MFMA with f32 accumulate
// (measured absmax 0.0156 << 0.069 threshold).
//
// FINAL: composition of per-kernel measured bests (session R4-R14):
//  - qkv: R4-exact fresh-loads, single LDS buffer, 2 barriers (130.9 us,
//    393 TF = this 128^2 2-barrier structure's shape floor). Probes that
//    measured WORSE: reg-dbuf (137), LDS-dbuf 1-barrier (134), A-direct
//    (236), global_load_lds DMA (203), bank-restride 36/68 (regression via
//    lost 16B alignment — LDS row stride must stay multiple of 16B).
//  - attn: R5 sequential paired-tile swapped-QK^T schedule (~125 us).
//    Paired q-tiles {ia, 31-ia} = constant work/block; in-register row
//    softmax (2 shfl); defer-max; phase-merge variant regressed (+23).
//  - proj: R5 2-phase reg-prefetch, 128^2 (~62 us). 64x128/4-blocks-CU
//    regressed (density loss > TLP gain).

__device__ inline void load8_f32(const float* p, float* o) {
  float4 a = *reinterpret_cast<const float4*>(p);
  float4 b = *reinterpret_cast<const float4*>(p + 4);
  o[0]=a.x; o[1]=a.y; o[2]=a.z; o[3]=a.w;
  o[4]=b.x; o[5]=b.y; o[6]=b.z; o[7]=b.w;
}
__device__ inline unsigned short f2bf_bits(float x) {
  return __builtin_bit_cast(unsigned short, __float2bfloat16(x));
}
__device__ inline unsigned pack2bf(float lo, float hi) {
  return (unsigned)f2bf_bits(lo) | ((unsigned)f2bf_bits(hi) << 16);
}
__device__ inline bf16x8 lds8(const unsigned short* p) {
  return __builtin_bit_cast(bf16x8, *reinterpret_cast<const uint4*>(p));
}
__device__ inline f32x4 mfma16(bf16x8 a, bf16x8 b, f32x4 c) {
  return __builtin_amdgcn_mfma_f32_16x16x32_bf16(a, b, c, 0, 0, 0);
}

// ---------- Kernel 1: QKV GEMM (MFMA)  X[8192,1024]f32 @ W[1024,3072]f32 + b ----------
// R4-exact: fresh loads at loop top; TLP hides latency.
__global__ __launch_bounds__(256)
void qkv_f(const float* __restrict__ X, const float* __restrict__ W,
           const float* __restrict__ bias,
           bf16* __restrict__ q, bf16* __restrict__ k, bf16* __restrict__ v)
{
  __shared__ __align__(16) unsigned short As[128][40];
  __shared__ __align__(16) unsigned short Bt[128][40];
  const int t  = threadIdx.x;
  const int wv = t >> 6, ln = t & 63;
  const int l15 = ln & 15, lg = ln >> 4;
  const int wr = wv >> 1, wc = wv & 1;

  int id = blockIdx.x;                      // 1536 = 8 * 192, XCD swizzle
  id = (id & 7) * 192 + (id >> 3);
  const int bn = id % 24, bm = id / 24;
  const int gm0 = bm * 128, gn0 = bn * 128;

  const int arow = t >> 1, akc = (t & 1) * 16;   // A: 2 thr/row, 16 f32 each
  const int bk2  = t >> 4, bn0 = (t & 15) * 8;   // B: k-pair, 8 n each
  const int kk   = 2 * bk2;

  const f32x4 zero4 = {0.f, 0.f, 0.f, 0.f};
  f32x4 acc[4][4];
#pragma unroll
  for (int m = 0; m < 4; m++)
#pragma unroll
    for (int n = 0; n < 4; n++) acc[m][n] = zero4;

  for (int kt = 0; kt < 1024; kt += 32) {
    { // A tile: f32 -> bf16
      float tmp[16];
      load8_f32(X + (size_t)(gm0 + arow) * 1024 + kt + akc, tmp);
      load8_f32(X + (size_t)(gm0 + arow) * 1024 + kt + akc + 8, tmp + 8);
      unsigned short u[16];
#pragma unroll
      for (int i = 0; i < 16; i++) u[i] = f2bf_bits(tmp[i]);
      *reinterpret_cast<uint4*>(&As[arow][akc])     = *reinterpret_cast<const uint4*>(u);
      *reinterpret_cast<uint4*>(&As[arow][akc + 8]) = *reinterpret_cast<const uint4*>(u + 8);
    }
    { // B tile: transpose W[k][n] -> Bt[n][k], packed k-pairs, chunk swizzle
      const float* wp = W + (size_t)(kt + kk) * 3072 + gn0 + bn0;
      float t0[8], t1[8];
      load8_f32(wp, t0);
      load8_f32(wp + 3072, t1);
#pragma unroll
      for (int j = 0; j < 8; j++) {
        const int n = bn0 + j;
        const int col = ((((kk >> 3) ^ ((n >> 4) & 3)) << 3) | (kk & 7));
        *reinterpret_cast<unsigned*>(&Bt[n][col]) = pack2bf(t0[j], t1[j]);
      }
    }
    __syncthreads();
    bf16x8 af[4], bfr[4];
#pragma unroll
    for (int m = 0; m < 4; m++) af[m] = lds8(&As[wr*64 + m*16 + l15][lg*8]);
#pragma unroll
    for (int n = 0; n < 4; n++) {
      const int nn = wc*64 + n*16 + l15;
      bfr[n] = lds8(&Bt[nn][(lg ^ ((nn >> 4) & 3)) << 3]);
    }
#pragma unroll
    for (int n = 0; n < 4; n++)
#pragma unroll
      for (int m = 0; m < 4; m++) acc[m][n] = mfma16(af[m], bfr[n], acc[m][n]);
    __syncthreads();
  }

#pragma unroll
  for (int nf = 0; nf < 4; nf++) {
    const int base_gc = gn0 + wc*64 + nf*16;
    const int which = base_gc >> 10;
    const int h = (base_gc & 1023) >> 6;
    const int d0 = (base_gc & 63) + l15;
    const float bvs = bias[base_gc + l15];
    bf16* dst = (which == 0) ? q : ((which == 1) ? k : v);
#pragma unroll
    for (int m = 0; m < 4; m++)
#pragma unroll
      for (int ri = 0; ri < 4; ri++) {
        const int gr = gm0 + wr*64 + m*16 + lg*4 + ri;
        const int bb = gr >> 11, s = gr & 2047;
        dst[((size_t)(bb*16 + h) * 2048 + s) * 64 + d0] =
            __float2bfloat16(acc[m][nf][ri] + bvs);
      }
  }
}

// ---------- Kernel 2: causal flash attention, paired q-tiles, swapped-QK^T ----------
// R5-exact sequential schedule. Block ia handles q-tiles {ia, 31-ia}:
// constant 33 tile-computations/block. S^T = mfma(A=K, B=Q): lane owns ONE
// q-row (l15) with 16 k-values in regs. PV: O^T = mfma(A=V^T, B=P^T).
__global__ __launch_bounds__(256, 4)
void attn_f(bf16* qo, const bf16* __restrict__ kg, const bf16* __restrict__ vg)
{
  __shared__ __align__(16) unsigned short Ks[64][72];
  __shared__ __align__(16) unsigned short Vt[64][72];
  __shared__ __align__(16) unsigned short Ps[4][16][72];

  const int t  = threadIdx.x;
  const int wv = t >> 6, ln = t & 63;
  const int l15 = ln & 15, lg = ln >> 4;
  const int ia = blockIdx.x, h = blockIdx.y, b = blockIdx.z;
  const int qtA = ia, qtB = 31 - ia;             // qtB > qtA always
  const size_t basebh = (size_t)(b * 16 + h) * 2048 * 64;
  const int qA0 = qtA * 64 + wv * 16;
  const int qB0 = qtB * 64 + wv * 16;

  auto loadq = [&](int q0, bf16x8* aq) {
    const bf16* qp = qo + basebh + (size_t)(q0 + l15) * 64 + lg * 8;
    uint4 u0 = *reinterpret_cast<const uint4*>(qp);
    uint4 u1 = *reinterpret_cast<const uint4*>(qp + 32);
    unsigned w[8] = {u0.x, u0.y, u0.z, u0.w, u1.x, u1.y, u1.z, u1.w};
    unsigned o[8];
#pragma unroll
    for (int i = 0; i < 8; i++) {
      float flo = __uint_as_float(w[i] << 16) * SC2;
      float fhi = __uint_as_float(w[i] & 0xffff0000u) * SC2;
      o[i] = pack2bf(flo, fhi);
    }
    aq[0] = __builtin_bit_cast(bf16x8, *reinterpret_cast<const uint4*>(o));
    aq[1] = __builtin_bit_cast(bf16x8, *reinterpret_cast<const uint4*>(o + 4));
  };
  bf16x8 aqA[2], aqB[2];
  loadq(qA0, aqA);
  loadq(qB0, aqB);

  const f32x4 zero4 = {0.f, 0.f, 0.f, 0.f};
  f32x4 accOA[4], accOB[4];                      // accO[f][r] = O[q=l15][d=f*16+lg*4+r]
  float mA = NEG_BIG, lA = 0.f, mB = NEG_BIG, lB = 0.f;
#pragma unroll
  for (int f = 0; f < 4; f++) { accOA[f] = zero4; accOB[f] = zero4; }

  const int kr = t >> 2, kc = (t & 3) * 16;      // K stage: 4 thr/row, 32B each
  const int vr = ln, vc = wv * 16;               // V stage: lane=kv row, wave=d chunk
  const bf16* kbase = kg + basebh;
  const bf16* vbase = vg + basebh;

  auto tile_compute = [&](int ct, int qt_this, const bf16x8* aq, f32x4* accO,
                          float& m_run, float& l_run) {
    f32x4 accS[4];
    __builtin_amdgcn_s_setprio(1);
#pragma unroll
    for (int f = 0; f < 4; f++) {
      bf16x8 b0 = lds8(&Ks[f*16 + l15][lg*8]);
      bf16x8 b1 = lds8(&Ks[f*16 + l15][32 + lg*8]);
      accS[f] = mfma16(b0, aq[0], zero4);        // A=K, B=Q -> S^T
      accS[f] = mfma16(b1, aq[1], accS[f]);
    }
    __builtin_amdgcn_s_setprio(0);

    float* s = reinterpret_cast<float*>(accS);   // s[f*4+r] = S[q=l15][k=f*16+lg*4+r]
    if (ct == qt_this) {                         // diagonal tile: causal mask
#pragma unroll
      for (int f = 0; f < 4; f++)
#pragma unroll
        for (int r = 0; r < 4; r++)
          if (f*16 + lg*4 + r > wv*16 + l15) s[f*4 + r] = NEG_BIG;
    }
    float t8[8];
#pragma unroll
    for (int i = 0; i < 8; i++) t8[i] = fmaxf(s[i], s[8 + i]);
    float t4a = fmaxf(t8[0], t8[4]), t4b = fmaxf(t8[1], t8[5]);
    float t4c = fmaxf(t8[2], t8[6]), t4d = fmaxf(t8[3], t8[7]);
    float mc = fmaxf(fmaxf(t4a, t4b), fmaxf(t4c, t4d));
    mc = fmaxf(mc, __shfl_xor(mc, 16));
    mc = fmaxf(mc, __shfl_xor(mc, 32));

    const float mn = fmaxf(m_run, mc);
    if (__any(mc > m_run)) {                     // defer-max: skip rescale if no growth
      const float al = exp2f(m_run - mn);
      float* ao = reinterpret_cast<float*>(accO);
#pragma unroll
      for (int i = 0; i < 16; i++) ao[i] *= al;
      l_run *= al;
    }
    m_run = mn;

    float ps = 0.f;
#pragma unroll
    for (int i = 0; i < 16; i++) { s[i] = exp2f(s[i] - mn); ps += s[i]; }
    ps += __shfl_xor(ps, 16);
    ps += __shfl_xor(ps, 32);
    l_run += ps;

#pragma unroll
    for (int f = 0; f < 4; f++)
#pragma unroll
      for (int c = 0; c < 2; c++)
        *reinterpret_cast<unsigned*>(&Ps[wv][l15][f*16 + lg*4 + 2*c]) =
            pack2bf(s[f*4 + 2*c], s[f*4 + 2*c + 1]);
    asm volatile("s_waitcnt lgkmcnt(0)" ::: "memory");
    __builtin_amdgcn_sched_barrier(0);

    bf16x8 ap0 = lds8(&Ps[wv][l15][lg*8]);       // B[k][col=l15] = P[l15][k]
    bf16x8 ap1 = lds8(&Ps[wv][l15][32 + lg*8]);
    __builtin_amdgcn_s_setprio(1);
#pragma unroll
    for (int f = 0; f < 4; f++) {
      bf16x8 bv0 = lds8(&Vt[f*16 + l15][lg*8]);
      bf16x8 bv1 = lds8(&Vt[f*16 + l15][32 + lg*8]);
      accO[f] = mfma16(bv0, ap0, accO[f]);
      accO[f] = mfma16(bv1, ap1, accO[f]);
    }
    __builtin_amdgcn_s_setprio(0);
  };

  uint4 k0 = *reinterpret_cast<const uint4*>(kbase + (size_t)kr * 64 + kc);
  uint4 k1 = *reinterpret_cast<const uint4*>(kbase + (size_t)kr * 64 + kc + 8);
  uint4 v0 = *reinterpret_cast<const uint4*>(vbase + (size_t)vr * 64 + vc);
  uint4 v1 = *reinterpret_cast<const uint4*>(vbase + (size_t)vr * 64 + vc + 8);

  for (int ct = 0; ct <= qtB; ct++) {
    *reinterpret_cast<uint4*>(&Ks[kr][kc])     = k0;
    *reinterpret_cast<uint4*>(&Ks[kr][kc + 8]) = k1;
    {
      unsigned w[8] = {v0.x, v0.y, v0.z, v0.w, v1.x, v1.y, v1.z, v1.w};
#pragma unroll
      for (int j = 0; j < 8; j++) {
        Vt[vc + 2*j][vr]     = (unsigned short)(w[j] & 0xffffu);
        Vt[vc + 2*j + 1][vr] = (unsigned short)(w[j] >> 16);
      }
    }
    __syncthreads();
    if (ct < qtB) {                              // issue next-tile loads early (T14)
      const size_t off = (size_t)(ct + 1) * 64 * 64;
      k0 = *reinterpret_cast<const uint4*>(kbase + off + (size_t)kr * 64 + kc);
      k1 = *reinterpret_cast<const uint4*>(kbase + off + (size_t)kr * 64 + kc + 8);
      v0 = *reinterpret_cast<const uint4*>(vbase + off + (size_t)vr * 64 + vc);
      v1 = *reinterpret_cast<const uint4*>(vbase + off + (size_t)vr * 64 + vc + 8);
    }
    tile_compute(ct, qtB, aqB, accOB, mB, lB);
    if (ct <= qtA) tile_compute(ct, qtA, aqA, accOA, mA, lA);
    __syncthreads();
  }

  const float invA = 1.f / lA, invB = 1.f / lB;
#pragma unroll
  for (int f = 0; f < 4; f++) {
    ushort4 sa, sb;
#pragma unroll
    for (int r = 0; r < 4; r++) {
      reinterpret_cast<unsigned short*>(&sa)[r] = f2bf_bits(accOA[f][r] * invA);
      reinterpret_cast<unsigned short*>(&sb)[r] = f2bf_bits(accOB[f][r] * invB);
    }
    *reinterpret_cast<ushort4*>(qo + basebh + (size_t)(qA0 + l15) * 64 + f*16 + lg*4) = sa;
    *reinterpret_cast<ushort4*>(qo + basebh + (size_t)(qB0 + l15) * 64 + f*16 + lg*4) = sb;
  }
}

// ---------- Kernel 3: projection (MFMA, 2-phase pipelined — R5-exact) ----------
__global__ __launch_bounds__(256)
void proj_f(const bf16* __restrict__ A, const float* __restrict__ W,
            const float* __restrict__ bias, float* __restrict__ out)
{
  __shared__ __align__(16) unsigned short As[128][40];
  __shared__ __align__(16) unsigned short Bt[128][40];
  const int t  = threadIdx.x;
  const int wv = t >> 6, ln = t & 63;
  const int l15 = ln & 15, lg = ln >> 4;
  const int wr = wv >> 1, wc = wv & 1;

  int id = blockIdx.x;                      // 512 = 8 * 64, XCD swizzle
  id = (id & 7) * 64 + (id >> 3);
  const int bn = id & 7, bm = id >> 3;
  const int gm0 = bm * 128, gn0 = bn * 128;

  const int arow = t >> 1, akc = (t & 1) * 16;
  const int bk2  = t >> 4, bn0 = (t & 15) * 8;
  const int kk   = 2 * bk2;

  const int gr_l = gm0 + arow;
  const int bb_l = gr_l >> 11, s_l = gr_l & 2047;
  const bf16* abase = A + ((size_t)bb_l * 16 * 2048 + (size_t)s_l) * 64;  // + h*131072 + d
  const float* wrow = W + (size_t)kk * 1024 + gn0 + bn0;

  const f32x4 zero4 = {0.f, 0.f, 0.f, 0.f};
  f32x4 acc[4][4];
#pragma unroll
  for (int m = 0; m < 4; m++)
#pragma unroll
    for (int n = 0; n < 4; n++) acc[m][n] = zero4;

  auto aptr = [&](int c) {
    const int hh = c >> 6, dd = c & 63;
    return abase + (size_t)hh * 131072 + dd;
  };

  uint4 au0, au1;
  float br0[8], br1[8];
  {
    const bf16* ap = aptr(akc);
    au0 = *reinterpret_cast<const uint4*>(ap);
    au1 = *reinterpret_cast<const uint4*>(ap + 8);
    load8_f32(wrow, br0);
    load8_f32(wrow + 1024, br1);
  }

  for (int kt = 0; kt < 1024; kt += 32) {
    *reinterpret_cast<uint4*>(&As[arow][akc])     = au0;
    *reinterpret_cast<uint4*>(&As[arow][akc + 8]) = au1;
#pragma unroll
    for (int j = 0; j < 8; j++) {
      const int n = bn0 + j;
      const int col = ((((kk >> 3) ^ ((n >> 4) & 3)) << 3) | (kk & 7));
      *reinterpret_cast<unsigned*>(&Bt[n][col]) = pack2bf(br0[j], br1[j]);
    }
    __syncthreads();
    if (kt + 32 < 1024) {
      const bf16* ap = aptr(kt + 32 + akc);
      au0 = *reinterpret_cast<const uint4*>(ap);
      au1 = *reinterpret_cast<const uint4*>(ap + 8);
      const float* wp = wrow + (size_t)(kt + 32) * 1024;
      load8_f32(wp, br0);
      load8_f32(wp + 1024, br1);
    }
    bf16x8 af[4], bfr[4];
#pragma unroll
    for (int m = 0; m < 4; m++) af[m] = lds8(&As[wr*64 + m*16 + l15][lg*8]);
#pragma unroll
    for (int n = 0; n < 4; n++) {
      const int nn = wc*64 + n*16 + l15;
      bfr[n] = lds8(&Bt[nn][(lg ^ ((nn >> 4) & 3)) << 3]);
    }
#pragma unroll
    for (int n = 0; n < 4; n++)
#pragma unroll
      for (int m = 0; m < 4; m++) acc[m][n] = mfma16(af[m], bfr[n], acc[m][n]);
    __syncthreads();
  }

#pragma unroll
  for (int nf = 0; nf < 4; nf++) {
    const int gc = gn0 + wc*64 + nf*16 + l15;
    const float bvs = bias[gc];
#pragma unroll
    for (int m = 0; m < 4; m++)
#pragma unroll
      for (int ri = 0; ri < 4; ri++) {
        const int gr = gm0 + wr*64 + m*16 + lg*4 + ri;
        out[(size_t)gr * 1024 + gc] = acc[m][nf][ri] + bvs;
      }
  }
}

extern "C" void kernel_launch(void* const* d_in, const int* in_sizes, int n_in,
                              void* d_out, int out_size, void* d_ws, size_t ws_size,
                              hipStream_t stream)
{
  const float *x = nullptr, *W_attn = nullptr, *b_attn = nullptr,
              *W_proj = nullptr, *b_proj = nullptr;
  for (int i = 0; i < n_in; i++) {
    switch (in_sizes[i]) {
      case 8388608: x      = (const float*)d_in[i]; break;  // [4,2048,1024]
      case 3145728: W_attn = (const float*)d_in[i]; break;  // [1024,3072]
      case 3072:    b_attn = (const float*)d_in[i]; break;
      case 1048576: W_proj = (const float*)d_in[i]; break;  // [1024,1024]
      case 1024:    b_proj = (const float*)d_in[i]; break;
      default: break;
    }
  }
  if (!x || !W_attn || !b_attn || !W_proj || !b_proj) {
    x = (const float*)d_in[0]; W_attn = (const float*)d_in[1];
    b_attn = (const float*)d_in[2]; W_proj = (const float*)d_in[3];
    b_proj = (const float*)d_in[4];
  }
  float* out = (float*)d_out;        // 8388608 f32 = 32 MiB

  // Memory plan (inputs never written; ws requirement 16 MiB):
  //   Q -> ws[0:16M)  bf16 BHSD      (later overwritten block-privately by O)
  //   K -> d_out bytes [0:16M)  bf16 BHSD   } dead before proj's f32 writes
  //   V -> d_out bytes [16M:32M) bf16 BHSD  }
  const size_t NE = 8388608;         // bf16 elements per 16 MiB tensor
  bf16* qb = (bf16*)d_ws;
  bf16* kb = (bf16*)d_out;
  bf16* vb = kb + NE;

  qkv_f <<<dim3(1536), 256, 0, stream>>>(x, W_attn, b_attn, qb, kb, vb);
  attn_f<<<dim3(16, 16, 4), 256, 0, stream>>>(qb, kb, vb);
  proj_f<<<dim3(512), 256, 0, stream>>>(qb, W_proj, b_proj, out);
}

// Round 16
// 318.293 us; speedup vs baseline: 1.0472x; 1.0244x over previous
//
#include <hip/hip_runtime.h>
#include <hip/hip_bf16.h>

typedef __hip_bfloat16 bf16;
typedef __bf16 bf16x8 __attribute__((ext_vector_type(8)));
typedef float f32x4 __attribute__((ext_vector_type(4)));
#define NEG_BIG (-3.0e38f)
#define SC2 0.18033688011112042f   /* 0.125 * log2(e): softmax in base-2 domain */

// All inputs and the output are FLOAT32 (per reference). Intermediates
// Q,K,V,O are bf16; GEMMs run bf16 MFMA with f32 accumulate
// (measured absmax 0.0156 << 0.069 threshold).
//
// R16 experiment (qkv only): qkv was AGPR+VGPR-occupancy-limited:
// VGPR 80 + acc 64 AGPR = 144/lane on the unified file -> 3 blocks/CU
// (observed 28% occupancy). Staging restructured into register-lean
// halves + __launch_bounds__(256,4) to reach <=64 VGPR -> 4 blocks/CU.
// attn/proj: byte-identical to the verified 326 us composition.

__device__ inline void load8_f32(const float* p, float* o) {
  float4 a = *reinterpret_cast<const float4*>(p);
  float4 b = *reinterpret_cast<const float4*>(p + 4);
  o[0]=a.x; o[1]=a.y; o[2]=a.z; o[3]=a.w;
  o[4]=b.x; o[5]=b.y; o[6]=b.z; o[7]=b.w;
}
__device__ inline unsigned short f2bf_bits(float x) {
  return __builtin_bit_cast(unsigned short, __float2bfloat16(x));
}
__device__ inline unsigned pack2bf(float lo, float hi) {
  return (unsigned)f2bf_bits(lo) | ((unsigned)f2bf_bits(hi) << 16);
}
__device__ inline bf16x8 lds8(const unsigned short* p) {
  return __builtin_bit_cast(bf16x8, *reinterpret_cast<const uint4*>(p));
}
__device__ inline f32x4 mfma16(bf16x8 a, bf16x8 b, f32x4 c) {
  return __builtin_amdgcn_mfma_f32_16x16x32_bf16(a, b, c, 0, 0, 0);
}

// ---------- Kernel 1: QKV GEMM (MFMA)  X[8192,1024]f32 @ W[1024,3072]f32 + b ----------
// Fresh loads each K-step (TLP hides latency), register-lean staging,
// launch_bounds(256,4): target <=64 VGPR so 64 VGPR + 64 AGPR = 4 blocks/CU.
__global__ __launch_bounds__(256, 4)
void qkv_f(const float* __restrict__ X, const float* __restrict__ W,
           const float* __restrict__ bias,
           bf16* __restrict__ q, bf16* __restrict__ k, bf16* __restrict__ v)
{
  __shared__ __align__(16) unsigned short As[128][40];
  __shared__ __align__(16) unsigned short Bt[128][40];
  const int t  = threadIdx.x;
  const int wv = t >> 6, ln = t & 63;
  const int l15 = ln & 15, lg = ln >> 4;
  const int wr = wv >> 1, wc = wv & 1;

  int id = blockIdx.x;                      // 1536 = 8 * 192, XCD swizzle
  id = (id & 7) * 192 + (id >> 3);
  const int bn = id % 24, bm = id / 24;
  const int gm0 = bm * 128, gn0 = bn * 128;

  const int ar4 = t >> 2, ac4 = (t & 3) * 8;     // A: 4 thr/row, 8 f32 each, 2 halves
  const int bk2 = t >> 4, bn0 = (t & 15) * 8;    // B: k-pair, 2 halves of 4 n
  const int kk  = 2 * bk2;

  const f32x4 zero4 = {0.f, 0.f, 0.f, 0.f};
  f32x4 acc[4][4];
#pragma unroll
  for (int m = 0; m < 4; m++)
#pragma unroll
    for (int n = 0; n < 4; n++) acc[m][n] = zero4;

  for (int kt = 0; kt < 1024; kt += 32) {
    // A tile: f32 -> bf16, two register-lean halves (rows ar4, ar4+64)
#pragma unroll
    for (int half = 0; half < 2; half++) {
      const int r = ar4 + half * 64;
      float tmp[8];
      load8_f32(X + (size_t)(gm0 + r) * 1024 + kt + ac4, tmp);
      unsigned uu[4];
#pragma unroll
      for (int i = 0; i < 4; i++) uu[i] = pack2bf(tmp[2*i], tmp[2*i+1]);
      *reinterpret_cast<uint4*>(&As[r][ac4]) = *reinterpret_cast<const uint4*>(uu);
    }
    // B tile: transpose W[k][n] -> Bt[n][k], two halves of 4 n each
#pragma unroll
    for (int half = 0; half < 2; half++) {
      const float* wp = W + (size_t)(kt + kk) * 3072 + gn0 + bn0 + half * 4;
      float4 q0 = *reinterpret_cast<const float4*>(wp);
      float4 q1 = *reinterpret_cast<const float4*>(wp + 3072);
      const float t0[4] = {q0.x, q0.y, q0.z, q0.w};
      const float t1[4] = {q1.x, q1.y, q1.z, q1.w};
#pragma unroll
      for (int j = 0; j < 4; j++) {
        const int n = bn0 + half * 4 + j;
        const int col = ((((kk >> 3) ^ ((n >> 4) & 3)) << 3) | (kk & 7));
        *reinterpret_cast<unsigned*>(&Bt[n][col]) = pack2bf(t0[j], t1[j]);
      }
    }
    __syncthreads();
    bf16x8 af[4], bfr[4];
#pragma unroll
    for (int m = 0; m < 4; m++) af[m] = lds8(&As[wr*64 + m*16 + l15][lg*8]);
#pragma unroll
    for (int n = 0; n < 4; n++) {
      const int nn = wc*64 + n*16 + l15;
      bfr[n] = lds8(&Bt[nn][(lg ^ ((nn >> 4) & 3)) << 3]);
    }
#pragma unroll
    for (int n = 0; n < 4; n++)
#pragma unroll
      for (int m = 0; m < 4; m++) acc[m][n] = mfma16(af[m], bfr[n], acc[m][n]);
    __syncthreads();
  }

#pragma unroll
  for (int nf = 0; nf < 4; nf++) {
    const int base_gc = gn0 + wc*64 + nf*16;
    const int which = base_gc >> 10;
    const int h = (base_gc & 1023) >> 6;
    const int d0 = (base_gc & 63) + l15;
    const float bvs = bias[base_gc + l15];
    bf16* dst = (which == 0) ? q : ((which == 1) ? k : v);
#pragma unroll
    for (int m = 0; m < 4; m++)
#pragma unroll
      for (int ri = 0; ri < 4; ri++) {
        const int gr = gm0 + wr*64 + m*16 + lg*4 + ri;
        const int bb = gr >> 11, s = gr & 2047;
        dst[((size_t)(bb*16 + h) * 2048 + s) * 64 + d0] =
            __float2bfloat16(acc[m][nf][ri] + bvs);
      }
  }
}

// ---------- Kernel 2: causal flash attention, paired q-tiles, swapped-QK^T ----------
// R5-exact sequential schedule. Block ia handles q-tiles {ia, 31-ia}:
// constant 33 tile-computations/block. S^T = mfma(A=K, B=Q): lane owns ONE
// q-row (l15) with 16 k-values in regs. PV: O^T = mfma(A=V^T, B=P^T).
__global__ __launch_bounds__(256, 4)
void attn_f(bf16* qo, const bf16* __restrict__ kg, const bf16* __restrict__ vg)
{
  __shared__ __align__(16) unsigned short Ks[64][72];
  __shared__ __align__(16) unsigned short Vt[64][72];
  __shared__ __align__(16) unsigned short Ps[4][16][72];

  const int t  = threadIdx.x;
  const int wv = t >> 6, ln = t & 63;
  const int l15 = ln & 15, lg = ln >> 4;
  const int ia = blockIdx.x, h = blockIdx.y, b = blockIdx.z;
  const int qtA = ia, qtB = 31 - ia;             // qtB > qtA always
  const size_t basebh = (size_t)(b * 16 + h) * 2048 * 64;
  const int qA0 = qtA * 64 + wv * 16;
  const int qB0 = qtB * 64 + wv * 16;

  auto loadq = [&](int q0, bf16x8* aq) {
    const bf16* qp = qo + basebh + (size_t)(q0 + l15) * 64 + lg * 8;
    uint4 u0 = *reinterpret_cast<const uint4*>(qp);
    uint4 u1 = *reinterpret_cast<const uint4*>(qp + 32);
    unsigned w[8] = {u0.x, u0.y, u0.z, u0.w, u1.x, u1.y, u1.z, u1.w};
    unsigned o[8];
#pragma unroll
    for (int i = 0; i < 8; i++) {
      float flo = __uint_as_float(w[i] << 16) * SC2;
      float fhi = __uint_as_float(w[i] & 0xffff0000u) * SC2;
      o[i] = pack2bf(flo, fhi);
    }
    aq[0] = __builtin_bit_cast(bf16x8, *reinterpret_cast<const uint4*>(o));
    aq[1] = __builtin_bit_cast(bf16x8, *reinterpret_cast<const uint4*>(o + 4));
  };
  bf16x8 aqA[2], aqB[2];
  loadq(qA0, aqA);
  loadq(qB0, aqB);

  const f32x4 zero4 = {0.f, 0.f, 0.f, 0.f};
  f32x4 accOA[4], accOB[4];                      // accO[f][r] = O[q=l15][d=f*16+lg*4+r]
  float mA = NEG_BIG, lA = 0.f, mB = NEG_BIG, lB = 0.f;
#pragma unroll
  for (int f = 0; f < 4; f++) { accOA[f] = zero4; accOB[f] = zero4; }

  const int kr = t >> 2, kc = (t & 3) * 16;      // K stage: 4 thr/row, 32B each
  const int vr = ln, vc = wv * 16;               // V stage: lane=kv row, wave=d chunk
  const bf16* kbase = kg + basebh;
  const bf16* vbase = vg + basebh;

  auto tile_compute = [&](int ct, int qt_this, const bf16x8* aq, f32x4* accO,
                          float& m_run, float& l_run) {
    f32x4 accS[4];
    __builtin_amdgcn_s_setprio(1);
#pragma unroll
    for (int f = 0; f < 4; f++) {
      bf16x8 b0 = lds8(&Ks[f*16 + l15][lg*8]);
      bf16x8 b1 = lds8(&Ks[f*16 + l15][32 + lg*8]);
      accS[f] = mfma16(b0, aq[0], zero4);        // A=K, B=Q -> S^T
      accS[f] = mfma16(b1, aq[1], accS[f]);
    }
    __builtin_amdgcn_s_setprio(0);

    float* s = reinterpret_cast<float*>(accS);   // s[f*4+r] = S[q=l15][k=f*16+lg*4+r]
    if (ct == qt_this) {                         // diagonal tile: causal mask
#pragma unroll
      for (int f = 0; f < 4; f++)
#pragma unroll
        for (int r = 0; r < 4; r++)
          if (f*16 + lg*4 + r > wv*16 + l15) s[f*4 + r] = NEG_BIG;
    }
    float t8[8];
#pragma unroll
    for (int i = 0; i < 8; i++) t8[i] = fmaxf(s[i], s[8 + i]);
    float t4a = fmaxf(t8[0], t8[4]), t4b = fmaxf(t8[1], t8[5]);
    float t4c = fmaxf(t8[2], t8[6]), t4d = fmaxf(t8[3], t8[7]);
    float mc = fmaxf(fmaxf(t4a, t4b), fmaxf(t4c, t4d));
    mc = fmaxf(mc, __shfl_xor(mc, 16));
    mc = fmaxf(mc, __shfl_xor(mc, 32));

    const float mn = fmaxf(m_run, mc);
    if (__any(mc > m_run)) {                     // defer-max: skip rescale if no growth
      const float al = exp2f(m_run - mn);
      float* ao = reinterpret_cast<float*>(accO);
#pragma unroll
      for (int i = 0; i < 16; i++) ao[i] *= al;
      l_run *= al;
    }
    m_run = mn;

    float ps = 0.f;
#pragma unroll
    for (int i = 0; i < 16; i++) { s[i] = exp2f(s[i] - mn); ps += s[i]; }
    ps += __shfl_xor(ps, 16);
    ps += __shfl_xor(ps, 32);
    l_run += ps;

#pragma unroll
    for (int f = 0; f < 4; f++)
#pragma unroll
      for (int c = 0; c < 2; c++)
        *reinterpret_cast<unsigned*>(&Ps[wv][l15][f*16 + lg*4 + 2*c]) =
            pack2bf(s[f*4 + 2*c], s[f*4 + 2*c + 1]);
    asm volatile("s_waitcnt lgkmcnt(0)" ::: "memory");
    __builtin_amdgcn_sched_barrier(0);

    bf16x8 ap0 = lds8(&Ps[wv][l15][lg*8]);       // B[k][col=l15] = P[l15][k]
    bf16x8 ap1 = lds8(&Ps[wv][l15][32 + lg*8]);
    __builtin_amdgcn_s_setprio(1);
#pragma unroll
    for (int f = 0; f < 4; f++) {
      bf16x8 bv0 = lds8(&Vt[f*16 + l15][lg*8]);
      bf16x8 bv1 = lds8(&Vt[f*16 + l15][32 + lg*8]);
      accO[f] = mfma16(bv0, ap0, accO[f]);
      accO[f] = mfma16(bv1, ap1, accO[f]);
    }
    __builtin_amdgcn_s_setprio(0);
  };

  uint4 k0 = *reinterpret_cast<const uint4*>(kbase + (size_t)kr * 64 + kc);
  uint4 k1 = *reinterpret_cast<const uint4*>(kbase + (size_t)kr * 64 + kc + 8);
  uint4 v0 = *reinterpret_cast<const uint4*>(vbase + (size_t)vr * 64 + vc);
  uint4 v1 = *reinterpret_cast<const uint4*>(vbase + (size_t)vr * 64 + vc + 8);

  for (int ct = 0; ct <= qtB; ct++) {
    *reinterpret_cast<uint4*>(&Ks[kr][kc])     = k0;
    *reinterpret_cast<uint4*>(&Ks[kr][kc + 8]) = k1;
    {
      unsigned w[8] = {v0.x, v0.y, v0.z, v0.w, v1.x, v1.y, v1.z, v1.w};
#pragma unroll
      for (int j = 0; j < 8; j++) {
        Vt[vc + 2*j][vr]     = (unsigned short)(w[j] & 0xffffu);
        Vt[vc + 2*j + 1][vr] = (unsigned short)(w[j] >> 16);
      }
    }
    __syncthreads();
    if (ct < qtB) {                              // issue next-tile loads early (T14)
      const size_t off = (size_t)(ct + 1) * 64 * 64;
      k0 = *reinterpret_cast<const uint4*>(kbase + off + (size_t)kr * 64 + kc);
      k1 = *reinterpret_cast<const uint4*>(kbase + off + (size_t)kr * 64 + kc + 8);
      v0 = *reinterpret_cast<const uint4*>(vbase + off + (size_t)vr * 64 + vc);
      v1 = *reinterpret_cast<const uint4*>(vbase + off + (size_t)vr * 64 + vc + 8);
    }
    tile_compute(ct, qtB, aqB, accOB, mB, lB);
    if (ct <= qtA) tile_compute(ct, qtA, aqA, accOA, mA, lA);
    __syncthreads();
  }

  const float invA = 1.f / lA, invB = 1.f / lB;
#pragma unroll
  for (int f = 0; f < 4; f++) {
    ushort4 sa, sb;
#pragma unroll
    for (int r = 0; r < 4; r++) {
      reinterpret_cast<unsigned short*>(&sa)[r] = f2bf_bits(accOA[f][r] * invA);
      reinterpret_cast<unsigned short*>(&sb)[r] = f2bf_bits(accOB[f][r] * invB);
    }
    *reinterpret_cast<ushort4*>(qo + basebh + (size_t)(qA0 + l15) * 64 + f*16 + lg*4) = sa;
    *reinterpret_cast<ushort4*>(qo + basebh + (size_t)(qB0 + l15) * 64 + f*16 + lg*4) = sb;
  }
}

// ---------- Kernel 3: projection (MFMA, 2-phase pipelined — R5-exact) ----------
__global__ __launch_bounds__(256)
void proj_f(const bf16* __restrict__ A, const float* __restrict__ W,
            const float* __restrict__ bias, float* __restrict__ out)
{
  __shared__ __align__(16) unsigned short As[128][40];
  __shared__ __align__(16) unsigned short Bt[128][40];
  const int t  = threadIdx.x;
  const int wv = t >> 6, ln = t & 63;
  const int l15 = ln & 15, lg = ln >> 4;
  const int wr = wv >> 1, wc = wv & 1;

  int id = blockIdx.x;                      // 512 = 8 * 64, XCD swizzle
  id = (id & 7) * 64 + (id >> 3);
  const int bn = id & 7, bm = id >> 3;
  const int gm0 = bm * 128, gn0 = bn * 128;

  const int arow = t >> 1, akc = (t & 1) * 16;
  const int bk2  = t >> 4, bn0 = (t & 15) * 8;
  const int kk   = 2 * bk2;

  const int gr_l = gm0 + arow;
  const int bb_l = gr_l >> 11, s_l = gr_l & 2047;
  const bf16* abase = A + ((size_t)bb_l * 16 * 2048 + (size_t)s_l) * 64;  // + h*131072 + d
  const float* wrow = W + (size_t)kk * 1024 + gn0 + bn0;

  const f32x4 zero4 = {0.f, 0.f, 0.f, 0.f};
  f32x4 acc[4][4];
#pragma unroll
  for (int m = 0; m < 4; m++)
#pragma unroll
    for (int n = 0; n < 4; n++) acc[m][n] = zero4;

  auto aptr = [&](int c) {
    const int hh = c >> 6, dd = c & 63;
    return abase + (size_t)hh * 131072 + dd;
  };

  uint4 au0, au1;
  float br0[8], br1[8];
  {
    const bf16* ap = aptr(akc);
    au0 = *reinterpret_cast<const uint4*>(ap);
    au1 = *reinterpret_cast<const uint4*>(ap + 8);
    load8_f32(wrow, br0);
    load8_f32(wrow + 1024, br1);
  }

  for (int kt = 0; kt < 1024; kt += 32) {
    *reinterpret_cast<uint4*>(&As[arow][akc])     = au0;
    *reinterpret_cast<uint4*>(&As[arow][akc + 8]) = au1;
#pragma unroll
    for (int j = 0; j < 8; j++) {
      const int n = bn0 + j;
      const int col = ((((kk >> 3) ^ ((n >> 4) & 3)) << 3) | (kk & 7));
      *reinterpret_cast<unsigned*>(&Bt[n][col]) = pack2bf(br0[j], br1[j]);
    }
    __syncthreads();
    if (kt + 32 < 1024) {
      const bf16* ap = aptr(kt + 32 + akc);
      au0 = *reinterpret_cast<const uint4*>(ap);
      au1 = *reinterpret_cast<const uint4*>(ap + 8);
      const float* wp = wrow + (size_t)(kt + 32) * 1024;
      load8_f32(wp, br0);
      load8_f32(wp + 1024, br1);
    }
    bf16x8 af[4], bfr[4];
#pragma unroll
    for (int m = 0; m < 4; m++) af[m] = lds8(&As[wr*64 + m*16 + l15][lg*8]);
#pragma unroll
    for (int n = 0; n < 4; n++) {
      const int nn = wc*64 + n*16 + l15;
      bfr[n] = lds8(&Bt[nn][(lg ^ ((nn >> 4) & 3)) << 3]);
    }
#pragma unroll
    for (int n = 0; n < 4; n++)
#pragma unroll
      for (int m = 0; m < 4; m++) acc[m][n] = mfma16(af[m], bfr[n], acc[m][n]);
    __syncthreads();
  }

#pragma unroll
  for (int nf = 0; nf < 4; nf++) {
    const int gc = gn0 + wc*64 + nf*16 + l15;
    const float bvs = bias[gc];
#pragma unroll
    for (int m = 0; m < 4; m++)
#pragma unroll
      for (int ri = 0; ri < 4; ri++) {
        const int gr = gm0 + wr*64 + m*16 + lg*4 + ri;
        out[(size_t)gr * 1024 + gc] = acc[m][nf][ri] + bvs;
      }
  }
}

extern "C" void kernel_launch(void* const* d_in, const int* in_sizes, int n_in,
                              void* d_out, int out_size, void* d_ws, size_t ws_size,
                              hipStream_t stream)
{
  const float *x = nullptr, *W_attn = nullptr, *b_attn = nullptr,
              *W_proj = nullptr, *b_proj = nullptr;
  for (int i = 0; i < n_in; i++) {
    switch (in_sizes[i]) {
      case 8388608: x      = (const float*)d_in[i]; break;  // [4,2048,1024]
      case 3145728: W_attn = (const float*)d_in[i]; break;  // [1024,3072]
      case 3072:    b_attn = (const float*)d_in[i]; break;
      case 1048576: W_proj = (const float*)d_in[i]; break;  // [1024,1024]
      case 1024:    b_proj = (const float*)d_in[i]; break;
      default: break;
    }
  }
  if (!x || !W_attn || !b_attn || !W_proj || !b_proj) {
    x = (const float*)d_in[0]; W_attn = (const float*)d_in[1];
    b_attn = (const float*)d_in[2]; W_proj = (const float*)d_in[3];
    b_proj = (const float*)d_in[4];
  }
  float* out = (float*)d_out;        // 8388608 f32 = 32 MiB

  // Memory plan (inputs never written; ws requirement 16 MiB):
  //   Q -> ws[0:16M)  bf16 BHSD      (later overwritten block-privately by O)
  //   K -> d_out bytes [0:16M)  bf16 BHSD   } dead before proj's f32 writes
  //   V -> d_out bytes [16M:32M) bf16 BHSD  }
  const size_t NE = 8388608;         // bf16 elements per 16 MiB tensor
  bf16* qb = (bf16*)d_ws;
  bf16* kb = (bf16*)d_out;
  bf16* vb = kb + NE;

  qkv_f <<<dim3(1536), 256, 0, stream>>>(x, W_attn, b_attn, qb, kb, vb);
  attn_f<<<dim3(16, 16, 4), 256, 0, stream>>>(qb, kb, vb);
  proj_f<<<dim3(512), 256, 0, stream>>>(qb, W_proj, b_proj, out);
}

// Round 17
// 306.053 us; speedup vs baseline: 1.0891x; 1.0400x over previous
//
#include <hip/hip_runtime.h>
#include <hip/hip_bf16.h>

typedef __hip_bfloat16 bf16;
typedef __bf16 bf16x8 __attribute__((ext_vector_type(8)));
typedef float f32x4 __attribute__((ext_vector_type(4)));
#define NEG_BIG (-3.0e38f)
#define SC2 0.18033688011112042f   /* 0.125 * log2(e): softmax in base-2 domain */

// All inputs and the output are FLOAT32 (per reference). Intermediates
// Q,K,V,O are bf16; GEMMs run bf16 MFMA with f32 accumulate
// (measured absmax 0.0156 << 0.069 threshold).
//
// Verified-best composition (session R4-R16, 318.3 us):
//  - qkv: fresh-loads 128^2 2-barrier + register-lean staging +
//    launch_bounds(256,4): VGPR 60 + 64 acc-AGPR = 124 < 128 -> 4 blocks/CU
//    (was 3 at VGPR 80). All pipelining probes measured worse.
//  - attn: R5 sequential paired-tile swapped-QK^T schedule; P-pack now
//    4x ds_write_b64 (R12-verified pattern) instead of 8x b32.
//  - proj: R5 2-phase reg-prefetch 128^2 (grid-limited at 2 blocks/CU;
//    64x128 variant measured worse).

__device__ inline void load8_f32(const float* p, float* o) {
  float4 a = *reinterpret_cast<const float4*>(p);
  float4 b = *reinterpret_cast<const float4*>(p + 4);
  o[0]=a.x; o[1]=a.y; o[2]=a.z; o[3]=a.w;
  o[4]=b.x; o[5]=b.y; o[6]=b.z; o[7]=b.w;
}
__device__ inline unsigned short f2bf_bits(float x) {
  return __builtin_bit_cast(unsigned short, __float2bfloat16(x));
}
__device__ inline unsigned pack2bf(float lo, float hi) {
  return (unsigned)f2bf_bits(lo) | ((unsigned)f2bf_bits(hi) << 16);
}
__device__ inline bf16x8 lds8(const unsigned short* p) {
  return __builtin_bit_cast(bf16x8, *reinterpret_cast<const uint4*>(p));
}
__device__ inline f32x4 mfma16(bf16x8 a, bf16x8 b, f32x4 c) {
  return __builtin_amdgcn_mfma_f32_16x16x32_bf16(a, b, c, 0, 0, 0);
}

// ---------- Kernel 1: QKV GEMM (MFMA)  X[8192,1024]f32 @ W[1024,3072]f32 + b ----------
// Fresh loads each K-step (TLP hides latency), register-lean staging,
// launch_bounds(256,4): 60 VGPR + 64 AGPR = 4 blocks/CU.
__global__ __launch_bounds__(256, 4)
void qkv_f(const float* __restrict__ X, const float* __restrict__ W,
           const float* __restrict__ bias,
           bf16* __restrict__ q, bf16* __restrict__ k, bf16* __restrict__ v)
{
  __shared__ __align__(16) unsigned short As[128][40];
  __shared__ __align__(16) unsigned short Bt[128][40];
  const int t  = threadIdx.x;
  const int wv = t >> 6, ln = t & 63;
  const int l15 = ln & 15, lg = ln >> 4;
  const int wr = wv >> 1, wc = wv & 1;

  int id = blockIdx.x;                      // 1536 = 8 * 192, XCD swizzle
  id = (id & 7) * 192 + (id >> 3);
  const int bn = id % 24, bm = id / 24;
  const int gm0 = bm * 128, gn0 = bn * 128;

  const int ar4 = t >> 2, ac4 = (t & 3) * 8;     // A: 4 thr/row, 8 f32 each, 2 halves
  const int bk2 = t >> 4, bn0 = (t & 15) * 8;    // B: k-pair, 2 halves of 4 n
  const int kk  = 2 * bk2;

  const f32x4 zero4 = {0.f, 0.f, 0.f, 0.f};
  f32x4 acc[4][4];
#pragma unroll
  for (int m = 0; m < 4; m++)
#pragma unroll
    for (int n = 0; n < 4; n++) acc[m][n] = zero4;

  for (int kt = 0; kt < 1024; kt += 32) {
    // A tile: f32 -> bf16, two register-lean halves (rows ar4, ar4+64)
#pragma unroll
    for (int half = 0; half < 2; half++) {
      const int r = ar4 + half * 64;
      float tmp[8];
      load8_f32(X + (size_t)(gm0 + r) * 1024 + kt + ac4, tmp);
      unsigned uu[4];
#pragma unroll
      for (int i = 0; i < 4; i++) uu[i] = pack2bf(tmp[2*i], tmp[2*i+1]);
      *reinterpret_cast<uint4*>(&As[r][ac4]) = *reinterpret_cast<const uint4*>(uu);
    }
    // B tile: transpose W[k][n] -> Bt[n][k], two halves of 4 n each
#pragma unroll
    for (int half = 0; half < 2; half++) {
      const float* wp = W + (size_t)(kt + kk) * 3072 + gn0 + bn0 + half * 4;
      float4 q0 = *reinterpret_cast<const float4*>(wp);
      float4 q1 = *reinterpret_cast<const float4*>(wp + 3072);
      const float t0[4] = {q0.x, q0.y, q0.z, q0.w};
      const float t1[4] = {q1.x, q1.y, q1.z, q1.w};
#pragma unroll
      for (int j = 0; j < 4; j++) {
        const int n = bn0 + half * 4 + j;
        const int col = ((((kk >> 3) ^ ((n >> 4) & 3)) << 3) | (kk & 7));
        *reinterpret_cast<unsigned*>(&Bt[n][col]) = pack2bf(t0[j], t1[j]);
      }
    }
    __syncthreads();
    bf16x8 af[4], bfr[4];
#pragma unroll
    for (int m = 0; m < 4; m++) af[m] = lds8(&As[wr*64 + m*16 + l15][lg*8]);
#pragma unroll
    for (int n = 0; n < 4; n++) {
      const int nn = wc*64 + n*16 + l15;
      bfr[n] = lds8(&Bt[nn][(lg ^ ((nn >> 4) & 3)) << 3]);
    }
#pragma unroll
    for (int n = 0; n < 4; n++)
#pragma unroll
      for (int m = 0; m < 4; m++) acc[m][n] = mfma16(af[m], bfr[n], acc[m][n]);
    __syncthreads();
  }

#pragma unroll
  for (int nf = 0; nf < 4; nf++) {
    const int base_gc = gn0 + wc*64 + nf*16;
    const int which = base_gc >> 10;
    const int h = (base_gc & 1023) >> 6;
    const int d0 = (base_gc & 63) + l15;
    const float bvs = bias[base_gc + l15];
    bf16* dst = (which == 0) ? q : ((which == 1) ? k : v);
#pragma unroll
    for (int m = 0; m < 4; m++)
#pragma unroll
      for (int ri = 0; ri < 4; ri++) {
        const int gr = gm0 + wr*64 + m*16 + lg*4 + ri;
        const int bb = gr >> 11, s = gr & 2047;
        dst[((size_t)(bb*16 + h) * 2048 + s) * 64 + d0] =
            __float2bfloat16(acc[m][nf][ri] + bvs);
      }
  }
}

// ---------- Kernel 2: causal flash attention, paired q-tiles, swapped-QK^T ----------
// R5-exact sequential schedule; P-pack via 4x ds_write_b64.
__global__ __launch_bounds__(256, 4)
void attn_f(bf16* qo, const bf16* __restrict__ kg, const bf16* __restrict__ vg)
{
  __shared__ __align__(16) unsigned short Ks[64][72];
  __shared__ __align__(16) unsigned short Vt[64][72];
  __shared__ __align__(16) unsigned short Ps[4][16][72];

  const int t  = threadIdx.x;
  const int wv = t >> 6, ln = t & 63;
  const int l15 = ln & 15, lg = ln >> 4;
  const int ia = blockIdx.x, h = blockIdx.y, b = blockIdx.z;
  const int qtA = ia, qtB = 31 - ia;             // qtB > qtA always
  const size_t basebh = (size_t)(b * 16 + h) * 2048 * 64;
  const int qA0 = qtA * 64 + wv * 16;
  const int qB0 = qtB * 64 + wv * 16;

  auto loadq = [&](int q0, bf16x8* aq) {
    const bf16* qp = qo + basebh + (size_t)(q0 + l15) * 64 + lg * 8;
    uint4 u0 = *reinterpret_cast<const uint4*>(qp);
    uint4 u1 = *reinterpret_cast<const uint4*>(qp + 32);
    unsigned w[8] = {u0.x, u0.y, u0.z, u0.w, u1.x, u1.y, u1.z, u1.w};
    unsigned o[8];
#pragma unroll
    for (int i = 0; i < 8; i++) {
      float flo = __uint_as_float(w[i] << 16) * SC2;
      float fhi = __uint_as_float(w[i] & 0xffff0000u) * SC2;
      o[i] = pack2bf(flo, fhi);
    }
    aq[0] = __builtin_bit_cast(bf16x8, *reinterpret_cast<const uint4*>(o));
    aq[1] = __builtin_bit_cast(bf16x8, *reinterpret_cast<const uint4*>(o + 4));
  };
  bf16x8 aqA[2], aqB[2];
  loadq(qA0, aqA);
  loadq(qB0, aqB);

  const f32x4 zero4 = {0.f, 0.f, 0.f, 0.f};
  f32x4 accOA[4], accOB[4];                      // accO[f][r] = O[q=l15][d=f*16+lg*4+r]
  float mA = NEG_BIG, lA = 0.f, mB = NEG_BIG, lB = 0.f;
#pragma unroll
  for (int f = 0; f < 4; f++) { accOA[f] = zero4; accOB[f] = zero4; }

  const int kr = t >> 2, kc = (t & 3) * 16;      // K stage: 4 thr/row, 32B each
  const int vr = ln, vc = wv * 16;               // V stage: lane=kv row, wave=d chunk
  const bf16* kbase = kg + basebh;
  const bf16* vbase = vg + basebh;

  auto tile_compute = [&](int ct, int qt_this, const bf16x8* aq, f32x4* accO,
                          float& m_run, float& l_run) {
    f32x4 accS[4];
    __builtin_amdgcn_s_setprio(1);
#pragma unroll
    for (int f = 0; f < 4; f++) {
      bf16x8 b0 = lds8(&Ks[f*16 + l15][lg*8]);
      bf16x8 b1 = lds8(&Ks[f*16 + l15][32 + lg*8]);
      accS[f] = mfma16(b0, aq[0], zero4);        // A=K, B=Q -> S^T
      accS[f] = mfma16(b1, aq[1], accS[f]);
    }
    __builtin_amdgcn_s_setprio(0);

    float* s = reinterpret_cast<float*>(accS);   // s[f*4+r] = S[q=l15][k=f*16+lg*4+r]
    if (ct == qt_this) {                         // diagonal tile: causal mask
#pragma unroll
      for (int f = 0; f < 4; f++)
#pragma unroll
        for (int r = 0; r < 4; r++)
          if (f*16 + lg*4 + r > wv*16 + l15) s[f*4 + r] = NEG_BIG;
    }
    float t8[8];
#pragma unroll
    for (int i = 0; i < 8; i++) t8[i] = fmaxf(s[i], s[8 + i]);
    float t4a = fmaxf(t8[0], t8[4]), t4b = fmaxf(t8[1], t8[5]);
    float t4c = fmaxf(t8[2], t8[6]), t4d = fmaxf(t8[3], t8[7]);
    float mc = fmaxf(fmaxf(t4a, t4b), fmaxf(t4c, t4d));
    mc = fmaxf(mc, __shfl_xor(mc, 16));
    mc = fmaxf(mc, __shfl_xor(mc, 32));

    const float mn = fmaxf(m_run, mc);
    if (__any(mc > m_run)) {                     // defer-max: skip rescale if no growth
      const float al = exp2f(m_run - mn);
      float* ao = reinterpret_cast<float*>(accO);
#pragma unroll
      for (int i = 0; i < 16; i++) ao[i] *= al;
      l_run *= al;
    }
    m_run = mn;

    float ps = 0.f;
#pragma unroll
    for (int i = 0; i < 16; i++) { s[i] = exp2f(s[i] - mn); ps += s[i]; }
    ps += __shfl_xor(ps, 16);
    ps += __shfl_xor(ps, 32);
    l_run += ps;

    // P pack -> LDS: 4 x ds_write_b64 (cols f*16+lg*4 .. +3 contiguous, 8B-aligned)
#pragma unroll
    for (int f = 0; f < 4; f++) {
      ushort4 u;
      u.x = f2bf_bits(s[f*4 + 0]); u.y = f2bf_bits(s[f*4 + 1]);
      u.z = f2bf_bits(s[f*4 + 2]); u.w = f2bf_bits(s[f*4 + 3]);
      *reinterpret_cast<ushort4*>(&Ps[wv][l15][f*16 + lg*4]) = u;
    }
    asm volatile("s_waitcnt lgkmcnt(0)" ::: "memory");
    __builtin_amdgcn_sched_barrier(0);

    bf16x8 ap0 = lds8(&Ps[wv][l15][lg*8]);       // B[k][col=l15] = P[l15][k]
    bf16x8 ap1 = lds8(&Ps[wv][l15][32 + lg*8]);
    __builtin_amdgcn_s_setprio(1);
#pragma unroll
    for (int f = 0; f < 4; f++) {
      bf16x8 bv0 = lds8(&Vt[f*16 + l15][lg*8]);
      bf16x8 bv1 = lds8(&Vt[f*16 + l15][32 + lg*8]);
      accO[f] = mfma16(bv0, ap0, accO[f]);
      accO[f] = mfma16(bv1, ap1, accO[f]);
    }
    __builtin_amdgcn_s_setprio(0);
  };

  uint4 k0 = *reinterpret_cast<const uint4*>(kbase + (size_t)kr * 64 + kc);
  uint4 k1 = *reinterpret_cast<const uint4*>(kbase + (size_t)kr * 64 + kc + 8);
  uint4 v0 = *reinterpret_cast<const uint4*>(vbase + (size_t)vr * 64 + vc);
  uint4 v1 = *reinterpret_cast<const uint4*>(vbase + (size_t)vr * 64 + vc + 8);

  for (int ct = 0; ct <= qtB; ct++) {
    *reinterpret_cast<uint4*>(&Ks[kr][kc])     = k0;
    *reinterpret_cast<uint4*>(&Ks[kr][kc + 8]) = k1;
    {
      unsigned w[8] = {v0.x, v0.y, v0.z, v0.w, v1.x, v1.y, v1.z, v1.w};
#pragma unroll
      for (int j = 0; j < 8; j++) {
        Vt[vc + 2*j][vr]     = (unsigned short)(w[j] & 0xffffu);
        Vt[vc + 2*j + 1][vr] = (unsigned short)(w[j] >> 16);
      }
    }
    __syncthreads();
    if (ct < qtB) {                              // issue next-tile loads early (T14)
      const size_t off = (size_t)(ct + 1) * 64 * 64;
      k0 = *reinterpret_cast<const uint4*>(kbase + off + (size_t)kr * 64 + kc);
      k1 = *reinterpret_cast<const uint4*>(kbase + off + (size_t)kr * 64 + kc + 8);
      v0 = *reinterpret_cast<const uint4*>(vbase + off + (size_t)vr * 64 + vc);
      v1 = *reinterpret_cast<const uint4*>(vbase + off + (size_t)vr * 64 + vc + 8);
    }
    tile_compute(ct, qtB, aqB, accOB, mB, lB);
    if (ct <= qtA) tile_compute(ct, qtA, aqA, accOA, mA, lA);
    __syncthreads();
  }

  const float invA = 1.f / lA, invB = 1.f / lB;
#pragma unroll
  for (int f = 0; f < 4; f++) {
    ushort4 sa, sb;
#pragma unroll
    for (int r = 0; r < 4; r++) {
      reinterpret_cast<unsigned short*>(&sa)[r] = f2bf_bits(accOA[f][r] * invA);
      reinterpret_cast<unsigned short*>(&sb)[r] = f2bf_bits(accOB[f][r] * invB);
    }
    *reinterpret_cast<ushort4*>(qo + basebh + (size_t)(qA0 + l15) * 64 + f*16 + lg*4) = sa;
    *reinterpret_cast<ushort4*>(qo + basebh + (size_t)(qB0 + l15) * 64 + f*16 + lg*4) = sb;
  }
}

// ---------- Kernel 3: projection (MFMA, 2-phase pipelined — R5-exact) ----------
__global__ __launch_bounds__(256)
void proj_f(const bf16* __restrict__ A, const float* __restrict__ W,
            const float* __restrict__ bias, float* __restrict__ out)
{
  __shared__ __align__(16) unsigned short As[128][40];
  __shared__ __align__(16) unsigned short Bt[128][40];
  const int t  = threadIdx.x;
  const int wv = t >> 6, ln = t & 63;
  const int l15 = ln & 15, lg = ln >> 4;
  const int wr = wv >> 1, wc = wv & 1;

  int id = blockIdx.x;                      // 512 = 8 * 64, XCD swizzle
  id = (id & 7) * 64 + (id >> 3);
  const int bn = id & 7, bm = id >> 3;
  const int gm0 = bm * 128, gn0 = bn * 128;

  const int arow = t >> 1, akc = (t & 1) * 16;
  const int bk2  = t >> 4, bn0 = (t & 15) * 8;
  const int kk   = 2 * bk2;

  const int gr_l = gm0 + arow;
  const int bb_l = gr_l >> 11, s_l = gr_l & 2047;
  const bf16* abase = A + ((size_t)bb_l * 16 * 2048 + (size_t)s_l) * 64;  // + h*131072 + d
  const float* wrow = W + (size_t)kk * 1024 + gn0 + bn0;

  const f32x4 zero4 = {0.f, 0.f, 0.f, 0.f};
  f32x4 acc[4][4];
#pragma unroll
  for (int m = 0; m < 4; m++)
#pragma unroll
    for (int n = 0; n < 4; n++) acc[m][n] = zero4;

  auto aptr = [&](int c) {
    const int hh = c >> 6, dd = c & 63;
    return abase + (size_t)hh * 131072 + dd;
  };

  uint4 au0, au1;
  float br0[8], br1[8];
  {
    const bf16* ap = aptr(akc);
    au0 = *reinterpret_cast<const uint4*>(ap);
    au1 = *reinterpret_cast<const uint4*>(ap + 8);
    load8_f32(wrow, br0);
    load8_f32(wrow + 1024, br1);
  }

  for (int kt = 0; kt < 1024; kt += 32) {
    *reinterpret_cast<uint4*>(&As[arow][akc])     = au0;
    *reinterpret_cast<uint4*>(&As[arow][akc + 8]) = au1;
#pragma unroll
    for (int j = 0; j < 8; j++) {
      const int n = bn0 + j;
      const int col = ((((kk >> 3) ^ ((n >> 4) & 3)) << 3) | (kk & 7));
      *reinterpret_cast<unsigned*>(&Bt[n][col]) = pack2bf(br0[j], br1[j]);
    }
    __syncthreads();
    if (kt + 32 < 1024) {
      const bf16* ap = aptr(kt + 32 + akc);
      au0 = *reinterpret_cast<const uint4*>(ap);
      au1 = *reinterpret_cast<const uint4*>(ap + 8);
      const float* wp = wrow + (size_t)(kt + 32) * 1024;
      load8_f32(wp, br0);
      load8_f32(wp + 1024, br1);
    }
    bf16x8 af[4], bfr[4];
#pragma unroll
    for (int m = 0; m < 4; m++) af[m] = lds8(&As[wr*64 + m*16 + l15][lg*8]);
#pragma unroll
    for (int n = 0; n < 4; n++) {
      const int nn = wc*64 + n*16 + l15;
      bfr[n] = lds8(&Bt[nn][(lg ^ ((nn >> 4) & 3)) << 3]);
    }
#pragma unroll
    for (int n = 0; n < 4; n++)
#pragma unroll
      for (int m = 0; m < 4; m++) acc[m][n] = mfma16(af[m], bfr[n], acc[m][n]);
    __syncthreads();
  }

#pragma unroll
  for (int nf = 0; nf < 4; nf++) {
    const int gc = gn0 + wc*64 + nf*16 + l15;
    const float bvs = bias[gc];
#pragma unroll
    for (int m = 0; m < 4; m++)
#pragma unroll
      for (int ri = 0; ri < 4; ri++) {
        const int gr = gm0 + wr*64 + m*16 + lg*4 + ri;
        out[(size_t)gr * 1024 + gc] = acc[m][nf][ri] + bvs;
      }
  }
}

extern "C" void kernel_launch(void* const* d_in, const int* in_sizes, int n_in,
                              void* d_out, int out_size, void* d_ws, size_t ws_size,
                              hipStream_t stream)
{
  const float *x = nullptr, *W_attn = nullptr, *b_attn = nullptr,
              *W_proj = nullptr, *b_proj = nullptr;
  for (int i = 0; i < n_in; i++) {
    switch (in_sizes[i]) {
      case 8388608: x      = (const float*)d_in[i]; break;  // [4,2048,1024]
      case 3145728: W_attn = (const float*)d_in[i]; break;  // [1024,3072]
      case 3072:    b_attn = (const float*)d_in[i]; break;
      case 1048576: W_proj = (const float*)d_in[i]; break;  // [1024,1024]
      case 1024:    b_proj = (const float*)d_in[i]; break;
      default: break;
    }
  }
  if (!x || !W_attn || !b_attn || !W_proj || !b_proj) {
    x = (const float*)d_in[0]; W_attn = (const float*)d_in[1];
    b_attn = (const float*)d_in[2]; W_proj = (const float*)d_in[3];
    b_proj = (const float*)d_in[4];
  }
  float* out = (float*)d_out;        // 8388608 f32 = 32 MiB

  // Memory plan (inputs never written; ws requirement 16 MiB):
  //   Q -> ws[0:16M)  bf16 BHSD      (later overwritten block-privately by O)
  //   K -> d_out bytes [0:16M)  bf16 BHSD   } dead before proj's f32 writes
  //   V -> d_out bytes [16M:32M) bf16 BHSD  }
  const size_t NE = 8388608;         // bf16 elements per 16 MiB tensor
  bf16* qb = (bf16*)d_ws;
  bf16* kb = (bf16*)d_out;
  bf16* vb = kb + NE;

  qkv_f <<<dim3(1536), 256, 0, stream>>>(x, W_attn, b_attn, qb, kb, vb);
  attn_f<<<dim3(16, 16, 4), 256, 0, stream>>>(qb, kb, vb);
  proj_f<<<dim3(512), 256, 0, stream>>>(qb, W_proj, b_proj, out);
}